// Round 11
// baseline (226.643 us; speedup 1.0000x reference)
//
#include <hip/hip_runtime.h>

#define N_EMB 8192
#define DIM   1024
#define NPAIR 65536
#define MARGIN 1.0f

// ws layout (bytes):
//   [0]      double acc
//   [8]      uint   cnt
//   [64]     int    bin_start[N_EMB+1]
//   [aligned] int   cursor[N_EMB]
//   [aligned] int   hist[N_EMB]
//   [aligned] int   packed[NPAIR]      ((b<<1)|t, sorted by a)
#define OFF_BIN   64
#define OFF_CUR   (OFF_BIN + (N_EMB + 1) * 4 + 4)      /* 8-aligned-ish, ints only */
#define OFF_HIST  (OFF_CUR + N_EMB * 4)
#define OFF_PACK  (OFF_HIST + N_EMB * 4)

// -------- K1: norms (wave-per-row) + zero hist/acc/cnt ----------------------
// 2048 blocks x 256 threads; wave handles one row; lane owns 4 float4.
__global__ __launch_bounds__(256) void norms_kernel(const float* __restrict__ emb,
                                                    float* __restrict__ rnorm,
                                                    int* __restrict__ hist,
                                                    double* __restrict__ acc,
                                                    unsigned int* __restrict__ cnt) {
    const int tid  = threadIdx.x;
    const int lane = tid & 63;
    const int row  = blockIdx.x * 4 + (tid >> 6);
    const float4* r = reinterpret_cast<const float4*>(emb + (size_t)row * DIM);
    const float4 v0 = r[lane];
    const float4 v1 = r[lane + 64];
    const float4 v2 = r[lane + 128];
    const float4 v3 = r[lane + 192];
    float s = v0.x*v0.x + v0.y*v0.y + v0.z*v0.z + v0.w*v0.w
            + v1.x*v1.x + v1.y*v1.y + v1.z*v1.z + v1.w*v1.w
            + v2.x*v2.x + v2.y*v2.y + v2.z*v2.z + v2.w*v2.w
            + v3.x*v3.x + v3.y*v3.y + v3.z*v3.z + v3.w*v3.w;
    #pragma unroll
    for (int off = 32; off > 0; off >>= 1) s += __shfl_xor(s, off);
    if (lane == 0) rnorm[row] = 1.0f / sqrtf(s);

    const int gid = blockIdx.x * 256 + tid;
    if (gid < N_EMB) hist[gid] = 0;
    if (gid == N_EMB) { *acc = 0.0; *cnt = 0u; }
}

// -------- K2: histogram of ind_one ------------------------------------------
__global__ __launch_bounds__(256) void hist_kernel(const int* __restrict__ ind1,
                                                   int* __restrict__ hist) {
    const int p = blockIdx.x * 256 + threadIdx.x;
    if (p < NPAIR) atomicAdd(&hist[ind1[p]], 1);
}

// -------- K3: exclusive scan over 8192 bins (1 block, 256 threads x 32) -----
__global__ __launch_bounds__(256) void scan_kernel(const int* __restrict__ hist,
                                                   int* __restrict__ bin_start,
                                                   int* __restrict__ cursor) {
    const int t = threadIdx.x;
    int loc[32];
    int run = 0;
    #pragma unroll
    for (int j = 0; j < 32; ++j) { loc[j] = run; run += hist[t * 32 + j]; }

    __shared__ int ps[256];
    ps[t] = run;
    __syncthreads();
    // Hillis-Steele inclusive scan
    for (int d = 1; d < 256; d <<= 1) {
        const int v = (t >= d) ? ps[t - d] : 0;
        __syncthreads();
        ps[t] += v;
        __syncthreads();
    }
    const int excl = ps[t] - run;   // exclusive prefix of this thread's chunk
    #pragma unroll
    for (int j = 0; j < 32; ++j) {
        const int b = excl + loc[j];
        bin_start[t * 32 + j] = b;
        cursor[t * 32 + j]    = b;
    }
    if (t == 255) bin_start[N_EMB] = NPAIR;
}

// -------- K4: scatter pairs into a-sorted order -----------------------------
__global__ __launch_bounds__(256) void scatter_kernel(const int* __restrict__ ind1,
                                                      const int* __restrict__ ind2,
                                                      const int* __restrict__ tgt,
                                                      int* __restrict__ cursor,
                                                      int* __restrict__ packed) {
    const int p = blockIdx.x * 256 + threadIdx.x;
    if (p < NPAIR) {
        const int a   = ind1[p];
        const int pos = atomicAdd(&cursor[a], 1);
        packed[pos] = (ind2[p] << 1) | (tgt[p] & 1);
    }
}

// -------- K5: pair kernel — wave w owns row a=w; a-row in registers ---------
__global__ __launch_bounds__(256, 8) void pair_kernel(const float* __restrict__ emb,
                                                      const float* __restrict__ rnorm,
                                                      const int* __restrict__ bin_start,
                                                      const int* __restrict__ packed,
                                                      double* __restrict__ acc,
                                                      unsigned int* __restrict__ cnt,
                                                      float* __restrict__ out) {
    const int lane = threadIdx.x & 63;
    const int w    = (blockIdx.x * blockDim.x + threadIdx.x) >> 6;  // row a

    const int start = bin_start[w];
    const int end   = bin_start[w + 1];

    // a-row resident in 16 VGPRs (coalesced, sequential across waves)
    const float4* ra = reinterpret_cast<const float4*>(emb + (size_t)w * DIM);
    const float4 a0 = ra[lane];
    const float4 a1 = ra[lane + 64];
    const float4 a2 = ra[lane + 128];
    const float4 a3 = ra[lane + 192];
    const float rna = rnorm[w];

    #define DOTA(S, B0, B1, B2, B3) do {                                      \
        S = a0.x*B0.x;                                                         \
        S = fmaf(a0.y,B0.y,S); S = fmaf(a0.z,B0.z,S); S = fmaf(a0.w,B0.w,S);   \
        S = fmaf(a1.x,B1.x,S); S = fmaf(a1.y,B1.y,S); S = fmaf(a1.z,B1.z,S);   \
        S = fmaf(a1.w,B1.w,S);                                                 \
        S = fmaf(a2.x,B2.x,S); S = fmaf(a2.y,B2.y,S); S = fmaf(a2.z,B2.z,S);   \
        S = fmaf(a2.w,B2.w,S);                                                 \
        S = fmaf(a3.x,B3.x,S); S = fmaf(a3.y,B3.y,S); S = fmaf(a3.z,B3.z,S);   \
        S = fmaf(a3.w,B3.w,S);                                                 \
    } while (0)

    float wsum = 0.0f;
    int i = start;

    // 2 pairs per iteration: 8 x 1KB b-loads in flight
    for (; i + 1 < end; i += 2) {
        const int pk0 = packed[i];
        const int pk1 = packed[i + 1];
        const int b0i = pk0 >> 1;
        const int b1i = pk1 >> 1;
        const float4* rb0 = reinterpret_cast<const float4*>(emb + (size_t)b0i * DIM);
        const float4* rb1 = reinterpret_cast<const float4*>(emb + (size_t)b1i * DIM);
        const float4 b00 = rb0[lane];
        const float4 b01 = rb0[lane + 64];
        const float4 b02 = rb0[lane + 128];
        const float4 b03 = rb0[lane + 192];
        const float4 b10 = rb1[lane];
        const float4 b11 = rb1[lane + 64];
        const float4 b12 = rb1[lane + 128];
        const float4 b13 = rb1[lane + 192];

        float s0, s1;
        DOTA(s0, b00, b01, b02, b03);
        DOTA(s1, b10, b11, b12, b13);

        #pragma unroll
        for (int off = 32; off > 0; off >>= 1) {
            s0 += __shfl_xor(s0, off);
            s1 += __shfl_xor(s1, off);
        }

        if (lane == 0) {
            const float d0 = 1.0f - s0 * rna * rnorm[b0i];
            const float t0 = (float)(pk0 & 1);
            wsum += t0 * d0 + (1.0f - t0) * fmaxf(MARGIN - d0, 0.0f);
            const float d1 = 1.0f - s1 * rna * rnorm[b1i];
            const float t1 = (float)(pk1 & 1);
            wsum += t1 * d1 + (1.0f - t1) * fmaxf(MARGIN - d1, 0.0f);
        }
    }
    // tail pair
    if (i < end) {
        const int pk = packed[i];
        const int bi = pk >> 1;
        const float4* rb = reinterpret_cast<const float4*>(emb + (size_t)bi * DIM);
        const float4 b0 = rb[lane];
        const float4 b1 = rb[lane + 64];
        const float4 b2 = rb[lane + 128];
        const float4 b3 = rb[lane + 192];
        float s;
        DOTA(s, b0, b1, b2, b3);
        #pragma unroll
        for (int off = 32; off > 0; off >>= 1) s += __shfl_xor(s, off);
        if (lane == 0) {
            const float d = 1.0f - s * rna * rnorm[bi];
            const float t = (float)(pk & 1);
            wsum += t * d + (1.0f - t) * fmaxf(MARGIN - d, 0.0f);
        }
    }
    #undef DOTA

    __shared__ float part[4];
    if (lane == 0) part[threadIdx.x >> 6] = wsum;
    __syncthreads();
    if (threadIdx.x == 0) {
        atomicAdd(acc, (double)(part[0] + part[1] + part[2] + part[3]));
        __threadfence();
        const unsigned int done = atomicAdd(cnt, 1u);
        if (done == gridDim.x - 1) {                 // last block finalizes
            const double tot = atomicAdd(acc, 0.0);  // device-scope read
            out[0] = (float)(tot / (double)NPAIR);
        }
    }
}

extern "C" void kernel_launch(void* const* d_in, const int* in_sizes, int n_in,
                              void* d_out, int out_size, void* d_ws, size_t ws_size,
                              hipStream_t stream) {
    const float* emb  = (const float*)d_in[0];
    const int*   ind1 = (const int*)d_in[1];
    const int*   ind2 = (const int*)d_in[2];
    const int*   tgt  = (const int*)d_in[3];
    float*       out  = (float*)d_out;

    char* ws = (char*)d_ws;
    double*       acc       = (double*)ws;
    unsigned int* cnt       = (unsigned int*)(ws + 8);
    int*          bin_start = (int*)(ws + OFF_BIN);
    int*          cursor    = (int*)(ws + OFF_CUR);
    int*          hist      = (int*)(ws + OFF_HIST);
    int*          packed    = (int*)(ws + OFF_PACK);
    // rnorm after packed, 4-aligned
    float*        rnorm     = (float*)(ws + OFF_PACK + (size_t)NPAIR * 4);

    norms_kernel<<<N_EMB / 4, 256, 0, stream>>>(emb, rnorm, hist, acc, cnt);
    hist_kernel<<<NPAIR / 256, 256, 0, stream>>>(ind1, hist);
    scan_kernel<<<1, 256, 0, stream>>>(hist, bin_start, cursor);
    scatter_kernel<<<NPAIR / 256, 256, 0, stream>>>(ind1, ind2, tgt, cursor, packed);
    pair_kernel<<<N_EMB / 4, 256, 0, stream>>>(emb, rnorm, bin_start, packed, acc, cnt, out);
}

// Round 17
// 195.176 us; speedup vs baseline: 1.1612x; 1.1612x over previous
//
#include <hip/hip_runtime.h>

#define N_EMB 8192
#define DIM   1024
#define NPAIR 65536
#define MARGIN 1.0f

// ws layout (bytes), all zero-init handled by K1:
#define OFF_BIN   64                                   /* int bin_start[N_EMB+1] */
#define OFF_CUR   (OFF_BIN  + (N_EMB + 1) * 4 + 4)     /* int cursor[N_EMB]      */
#define OFF_HIST  (OFF_CUR  + N_EMB * 4)               /* int hist[N_EMB]        */
#define OFF_PACK  (OFF_HIST + N_EMB * 4)               /* int packed[NPAIR]      */
#define OFF_ASRT  (OFF_PACK + NPAIR * 4)               /* int asort[NPAIR]       */
#define OFF_RNRM  (OFF_ASRT + NPAIR * 4)               /* float rnorm[N_EMB]     */

// -------- K1: norms (wave-per-row) + zero hist/acc/cnt ----------------------
__global__ __launch_bounds__(256) void norms_kernel(const float* __restrict__ emb,
                                                    float* __restrict__ rnorm,
                                                    int* __restrict__ hist,
                                                    double* __restrict__ acc,
                                                    unsigned int* __restrict__ cnt) {
    const int tid  = threadIdx.x;
    const int lane = tid & 63;
    const int row  = blockIdx.x * 4 + (tid >> 6);
    const float4* r = reinterpret_cast<const float4*>(emb + (size_t)row * DIM);
    const float4 v0 = r[lane];
    const float4 v1 = r[lane + 64];
    const float4 v2 = r[lane + 128];
    const float4 v3 = r[lane + 192];
    float s = v0.x*v0.x + v0.y*v0.y + v0.z*v0.z + v0.w*v0.w
            + v1.x*v1.x + v1.y*v1.y + v1.z*v1.z + v1.w*v1.w
            + v2.x*v2.x + v2.y*v2.y + v2.z*v2.z + v2.w*v2.w
            + v3.x*v3.x + v3.y*v3.y + v3.z*v3.z + v3.w*v3.w;
    #pragma unroll
    for (int off = 32; off > 0; off >>= 1) s += __shfl_xor(s, off);
    if (lane == 0) rnorm[row] = 1.0f / sqrtf(s);

    const int gid = blockIdx.x * 256 + tid;   // 0..524287
    if (gid < N_EMB) hist[gid] = 0;
    if (gid == N_EMB) { *acc = 0.0; *cnt = 0u; }
}

// -------- K2: histogram of ind_one ------------------------------------------
__global__ __launch_bounds__(256) void hist_kernel(const int* __restrict__ ind1,
                                                   int* __restrict__ hist) {
    const int p = blockIdx.x * 256 + threadIdx.x;
    if (p < NPAIR) atomicAdd(&hist[ind1[p]], 1);
}

// -------- K3: exclusive scan over 8192 bins (1 block) ------------------------
__global__ __launch_bounds__(256) void scan_kernel(const int* __restrict__ hist,
                                                   int* __restrict__ bin_start,
                                                   int* __restrict__ cursor) {
    const int t = threadIdx.x;
    int loc[32];
    int run = 0;
    #pragma unroll
    for (int j = 0; j < 32; ++j) { loc[j] = run; run += hist[t * 32 + j]; }

    __shared__ int ps[256];
    ps[t] = run;
    __syncthreads();
    for (int d = 1; d < 256; d <<= 1) {
        const int v = (t >= d) ? ps[t - d] : 0;
        __syncthreads();
        ps[t] += v;
        __syncthreads();
    }
    const int excl = ps[t] - run;
    #pragma unroll
    for (int j = 0; j < 32; ++j) {
        const int b = excl + loc[j];
        bin_start[t * 32 + j] = b;
        cursor[t * 32 + j]    = b;
    }
    if (t == 255) bin_start[N_EMB] = NPAIR;
}

// -------- K4: scatter pairs into a-sorted order ------------------------------
__global__ __launch_bounds__(256) void scatter_kernel(const int* __restrict__ ind1,
                                                      const int* __restrict__ ind2,
                                                      const int* __restrict__ tgt,
                                                      int* __restrict__ cursor,
                                                      int* __restrict__ packed,
                                                      int* __restrict__ asort) {
    const int p = blockIdx.x * 256 + threadIdx.x;
    if (p < NPAIR) {
        const int a   = ind1[p];
        const int pos = atomicAdd(&cursor[a], 1);
        packed[pos] = (ind2[p] << 1) | (tgt[p] & 1);
        asort[pos]  = a;
    }
}

// -------- K5: pair kernel — exactly 8 sorted pairs per wave ------------------
// a-row cached in registers, reloaded only when a changes (wave-uniform branch).
// b-rows: 2 pairs per step -> 8 x 1KB loads in flight (r4's proven depth).
__global__ __launch_bounds__(256) void pair_kernel(const float* __restrict__ emb,
                                                   const float* __restrict__ rnorm,
                                                   const int* __restrict__ packed,
                                                   const int* __restrict__ asort,
                                                   double* __restrict__ acc,
                                                   unsigned int* __restrict__ cnt,
                                                   float* __restrict__ out) {
    const int lane = threadIdx.x & 63;
    const int w    = (blockIdx.x * blockDim.x + threadIdx.x) >> 6;
    const int base = w * 8;

    float4 A0, A1, A2, A3;
    float  rna  = 0.0f;
    int    cura = -1;
    float  wsum = 0.0f;

    #define LOADA(AI) do {                                                     \
        const float4* ra = reinterpret_cast<const float4*>(emb + (size_t)(AI) * DIM); \
        A0 = ra[lane]; A1 = ra[lane + 64]; A2 = ra[lane + 128]; A3 = ra[lane + 192];  \
        rna = rnorm[AI]; cura = (AI);                                          \
    } while (0)

    #define DOTA(S, B0, B1, B2, B3) do {                                       \
        S = A0.x*B0.x;                                                         \
        S = fmaf(A0.y,B0.y,S); S = fmaf(A0.z,B0.z,S); S = fmaf(A0.w,B0.w,S);   \
        S = fmaf(A1.x,B1.x,S); S = fmaf(A1.y,B1.y,S); S = fmaf(A1.z,B1.z,S);   \
        S = fmaf(A1.w,B1.w,S);                                                 \
        S = fmaf(A2.x,B2.x,S); S = fmaf(A2.y,B2.y,S); S = fmaf(A2.z,B2.z,S);   \
        S = fmaf(A2.w,B2.w,S);                                                 \
        S = fmaf(A3.x,B3.x,S); S = fmaf(A3.y,B3.y,S); S = fmaf(A3.z,B3.z,S);   \
        S = fmaf(A3.w,B3.w,S);                                                 \
    } while (0)

    #pragma unroll
    for (int i = 0; i < 8; i += 2) {
        const int p0  = base + i;
        const int p1  = p0 + 1;
        const int pk0 = packed[p0];
        const int pk1 = packed[p1];
        const int av0 = asort[p0];
        const int av1 = asort[p1];
        const int bv0 = pk0 >> 1;
        const int bv1 = pk1 >> 1;

        // issue both b-row loads first (8 x 1KB in flight)
        const float4* rb0 = reinterpret_cast<const float4*>(emb + (size_t)bv0 * DIM);
        const float4* rb1 = reinterpret_cast<const float4*>(emb + (size_t)bv1 * DIM);
        const float4 B00 = rb0[lane];
        const float4 B01 = rb0[lane + 64];
        const float4 B02 = rb0[lane + 128];
        const float4 B03 = rb0[lane + 192];
        const float4 B10 = rb1[lane];
        const float4 B11 = rb1[lane + 64];
        const float4 B12 = rb1[lane + 128];
        const float4 B13 = rb1[lane + 192];

        if (av0 != cura) LOADA(av0);       // wave-uniform branch
        float s0;
        DOTA(s0, B00, B01, B02, B03);
        const float rna0 = rna;

        if (av1 != cura) LOADA(av1);
        float s1;
        DOTA(s1, B10, B11, B12, B13);
        const float rna1 = rna;

        #pragma unroll
        for (int off = 32; off > 0; off >>= 1) {
            s0 += __shfl_xor(s0, off);
            s1 += __shfl_xor(s1, off);
        }

        if (lane == 0) {
            const float d0 = 1.0f - s0 * rna0 * rnorm[bv0];
            const float t0 = (float)(pk0 & 1);
            wsum += t0 * d0 + (1.0f - t0) * fmaxf(MARGIN - d0, 0.0f);
            const float d1 = 1.0f - s1 * rna1 * rnorm[bv1];
            const float t1 = (float)(pk1 & 1);
            wsum += t1 * d1 + (1.0f - t1) * fmaxf(MARGIN - d1, 0.0f);
        }
    }
    #undef DOTA
    #undef LOADA

    __shared__ float part[4];
    if (lane == 0) part[threadIdx.x >> 6] = wsum;
    __syncthreads();
    if (threadIdx.x == 0) {
        atomicAdd(acc, (double)(part[0] + part[1] + part[2] + part[3]));
        __threadfence();
        const unsigned int done = atomicAdd(cnt, 1u);
        if (done == gridDim.x - 1) {
            const double tot = atomicAdd(acc, 0.0);
            out[0] = (float)(tot / (double)NPAIR);
        }
    }
}

extern "C" void kernel_launch(void* const* d_in, const int* in_sizes, int n_in,
                              void* d_out, int out_size, void* d_ws, size_t ws_size,
                              hipStream_t stream) {
    const float* emb  = (const float*)d_in[0];
    const int*   ind1 = (const int*)d_in[1];
    const int*   ind2 = (const int*)d_in[2];
    const int*   tgt  = (const int*)d_in[3];
    float*       out  = (float*)d_out;

    char* ws = (char*)d_ws;
    double*       acc       = (double*)ws;
    unsigned int* cnt       = (unsigned int*)(ws + 8);
    int*          bin_start = (int*)(ws + OFF_BIN);
    int*          cursor    = (int*)(ws + OFF_CUR);
    int*          hist      = (int*)(ws + OFF_HIST);
    int*          packed    = (int*)(ws + OFF_PACK);
    int*          asort     = (int*)(ws + OFF_ASRT);
    float*        rnorm     = (float*)(ws + OFF_RNRM);

    norms_kernel<<<N_EMB / 4, 256, 0, stream>>>(emb, rnorm, hist, acc, cnt);
    hist_kernel<<<NPAIR / 256, 256, 0, stream>>>(ind1, hist);
    scan_kernel<<<1, 256, 0, stream>>>(hist, bin_start, cursor);
    scatter_kernel<<<NPAIR / 256, 256, 0, stream>>>(ind1, ind2, tgt, cursor, packed, asort);
    pair_kernel<<<NPAIR / 8 / 4, 256, 0, stream>>>(emb, rnorm, packed, asort, acc, cnt, out);
}